// Round 1
// baseline (622.231 us; speedup 1.0000x reference)
//
#include <hip/hip_runtime.h>

#define C 64
#define K 1024
#define HW 4096
#define N_TOTAL 131072   // 32*64*64
#define OUT0 8388608     // 32*64*64*64 (z_q_out elements)

// ---------------------------------------------------------------------------
// Kernel 1: per-code squared norms ||e_k||^2, replicating numpy pairwise
// 8-accumulator summation order, NO fma contraction (numpy rounds e^2 first).
// ---------------------------------------------------------------------------
__global__ __launch_bounds__(256) void ek_kernel(const float* __restrict__ E,
                                                 float* __restrict__ ek) {
#pragma clang fp contract(off)
    int k = blockIdx.x * 256 + threadIdx.x;
    if (k >= K) return;
    const float* e = E + k * C;
    float r[8];
#pragma unroll
    for (int j = 0; j < 8; ++j) { float v = e[j]; r[j] = v * v; }
#pragma unroll
    for (int i = 8; i < C; i += 8) {
#pragma unroll
        for (int j = 0; j < 8; ++j) { float v = e[i + j]; r[j] += v * v; }
    }
    ek[k] = ((r[0] + r[1]) + (r[2] + r[3])) + ((r[4] + r[5]) + (r[6] + r[7]));
}

// ---------------------------------------------------------------------------
// Kernel 2: main VQ kernel. One thread per spatial vector n=(b,h,w).
//  - load z row (strided over c, coalesced across lanes) into 64 VGPRs
//  - zn = ||z||^2 in numpy pairwise order (no fma)
//  - scan K codes: d = fl(fl(zn+ek) - 2*dot)  with dot via sequential fma
//    (e rows are wave-uniform -> scalar loads + v_fmac v,s,v)
//  - strict < scan ascending k == numpy argmin lowest-index tie-break
//  - epilogue: z_q_st = fl(z + fl(e-z)) (replicates straight-through double
//    rounding), per-thread loss partial, wave-reduced.
// ---------------------------------------------------------------------------
__global__ __launch_bounds__(256) void vq_kernel(const float* __restrict__ Z,
                                                 const float* __restrict__ E,
                                                 const float* __restrict__ ek,
                                                 float* __restrict__ out,
                                                 float* __restrict__ partials) {
#pragma clang fp contract(off)
    int n = blockIdx.x * 256 + threadIdx.x;
    int b = n >> 12;          // HW = 4096
    int hw = n & 4095;
    const float* zp = Z + b * (C * HW) + hw;

    float z[C];
#pragma unroll
    for (int c = 0; c < C; ++c) z[c] = zp[c * HW];

    // ||z||^2, numpy pairwise 8-accumulator order, squares rounded separately
    float zn;
    {
        float r[8];
#pragma unroll
        for (int j = 0; j < 8; ++j) r[j] = z[j] * z[j];
#pragma unroll
        for (int i = 8; i < C; i += 8) {
#pragma unroll
            for (int j = 0; j < 8; ++j) r[j] += z[i + j] * z[i + j];
        }
        zn = ((r[0] + r[1]) + (r[2] + r[3])) + ((r[4] + r[5]) + (r[6] + r[7]));
    }

    float dmin = __builtin_inff();
    int best = 0;
#pragma unroll 1
    for (int k = 0; k < K; k += 2) {
        const float* e0 = E + k * C;
        const float* e1 = e0 + C;
        float a0 = 0.0f, a1 = 0.0f;
#pragma unroll
        for (int c = 0; c < C; ++c) {
            a0 = __builtin_fmaf(z[c], e0[c], a0);
            a1 = __builtin_fmaf(z[c], e1[c], a1);
        }
        // fl(fl(zn+ek) - 2*a): 2*a is exact, so fused or not is identical
        float A0 = zn + ek[k];
        float A1 = zn + ek[k + 1];
        float d0 = A0 - 2.0f * a0;
        float d1 = A1 - 2.0f * a1;
        if (d0 < dmin) { dmin = d0; best = k; }
        if (d1 < dmin) { dmin = d1; best = k + 1; }
    }

    // epilogue: quantized output (with straight-through double rounding),
    // index, loss partial
    const float* eb = E + best * C;
    float* o0 = out + b * (C * HW) + hw;
    float ls = 0.0f;
#pragma unroll
    for (int c = 0; c < C; ++c) {
        float e  = eb[c];
        float df = e - z[c];      // fl(z_q - z)
        float q  = z[c] + df;     // fl(z + fl(z_q - z))  (straight-through)
        o0[c * HW] = q;
        ls += df * df;            // squared diff, rounded like numpy
    }
    out[OUT0 + n] = (float)best;  // indices region, as float

    // deterministic wave-64 butterfly reduce
#pragma unroll
    for (int off = 32; off > 0; off >>= 1) ls += __shfl_xor(ls, off, 64);
    int wid = n >> 6;
    if ((threadIdx.x & 63) == 0) partials[wid] = ls;
}

// ---------------------------------------------------------------------------
// Kernel 3: deterministic final loss reduction in fp64.
// loss = m + 0.25*m, m = mean(diff^2)  (both loss terms are numerically equal)
// ---------------------------------------------------------------------------
__global__ __launch_bounds__(256) void loss_kernel(const float* __restrict__ partials,
                                                   float* __restrict__ out) {
    __shared__ double sm[256];
    int t = threadIdx.x;
    double s = 0.0;
    for (int i = t; i < (N_TOTAL / 64); i += 256) s += (double)partials[i];
    sm[t] = s;
    __syncthreads();
    for (int o = 128; o > 0; o >>= 1) {
        if (t < o) sm[t] += sm[t + o];
        __syncthreads();
    }
    if (t == 0) {
        float m = (float)(sm[0] * (1.0 / 8388608.0));  // /2^23 exact scale
        float loss = m + 0.25f * m;
        out[OUT0 + N_TOTAL] = loss;
    }
}

extern "C" void kernel_launch(void* const* d_in, const int* in_sizes, int n_in,
                              void* d_out, int out_size, void* d_ws, size_t ws_size,
                              hipStream_t stream) {
    const float* Z = (const float*)d_in[0];   // [32,64,64,64] fp32
    const float* E = (const float*)d_in[1];   // [1024,64] fp32
    float* out = (float*)d_out;
    float* ek = (float*)d_ws;                 // 1024 floats
    float* partials = ek + K;                 // 2048 floats

    hipLaunchKernelGGL(ek_kernel, dim3(4), dim3(256), 0, stream, E, ek);
    hipLaunchKernelGGL(vq_kernel, dim3(N_TOTAL / 256), dim3(256), 0, stream,
                       Z, E, ek, out, partials);
    hipLaunchKernelGGL(loss_kernel, dim3(1), dim3(256), 0, stream, partials, out);
}

// Round 2
// 474.433 us; speedup vs baseline: 1.3115x; 1.3115x over previous
//
#include <hip/hip_runtime.h>

#define C 64
#define K 1024
#define HW 4096
#define N_TOTAL 131072   // 32*64*64
#define OUT0 8388608     // 32*64*64*64 (z_q_out elements)

// ---------------------------------------------------------------------------
// Kernel 1: per-code squared norms ||e_k||^2, replicating numpy pairwise
// 8-accumulator summation order, NO fma contraction (numpy rounds e^2 first).
// ---------------------------------------------------------------------------
__global__ __launch_bounds__(256) void ek_kernel(const float* __restrict__ E,
                                                 float* __restrict__ ek) {
#pragma clang fp contract(off)
    int k = blockIdx.x * 256 + threadIdx.x;
    if (k >= K) return;
    const float* e = E + k * C;
    float r[8];
#pragma unroll
    for (int j = 0; j < 8; ++j) { float v = e[j]; r[j] = v * v; }
#pragma unroll
    for (int i = 8; i < C; i += 8) {
#pragma unroll
        for (int j = 0; j < 8; ++j) { float v = e[i + j]; r[j] += v * v; }
    }
    ek[k] = ((r[0] + r[1]) + (r[2] + r[3])) + ((r[4] + r[5]) + (r[6] + r[7]));
}

// ---------------------------------------------------------------------------
// Kernel 2: main VQ kernel. One thread per spatial vector n=(b,h,w).
// __launch_bounds__(256,2): 2 waves/SIMD -> 256-VGPR budget so the 64-float
// z row stays RESIDENT in VGPRs (R1's (256) default allocated only 48 VGPRs
// and re-streamed z from L1 every K iteration -> VALUBusy 40%).
// K-loop unrolled x4: 4 independent fma chains (latency 4cy / issue 2cy).
// E-row addresses are wave-uniform -> scalar s_load path, off the VALU pipe.
// Numerics FROZEN (absmax 0.0 in R1): pairwise-8 zn, sequential-fma dot,
// d = fl(fl(zn+ek) - 2a), strict < ascending-k tie-break.
// ---------------------------------------------------------------------------
__global__ __launch_bounds__(256, 2) void vq_kernel(const float* __restrict__ Z,
                                                    const float* __restrict__ E,
                                                    const float* __restrict__ ek,
                                                    float* __restrict__ out,
                                                    float* __restrict__ partials) {
#pragma clang fp contract(off)
    int n = blockIdx.x * 256 + threadIdx.x;
    int b = n >> 12;          // HW = 4096
    int hw = n & 4095;
    const float* zp = Z + b * (C * HW) + hw;

    float z[C];
#pragma unroll
    for (int c = 0; c < C; ++c) z[c] = zp[c * HW];

    // ||z||^2, numpy pairwise 8-accumulator order, squares rounded separately
    float zn;
    {
        float r[8];
#pragma unroll
        for (int j = 0; j < 8; ++j) r[j] = z[j] * z[j];
#pragma unroll
        for (int i = 8; i < C; i += 8) {
#pragma unroll
            for (int j = 0; j < 8; ++j) r[j] += z[i + j] * z[i + j];
        }
        zn = ((r[0] + r[1]) + (r[2] + r[3])) + ((r[4] + r[5]) + (r[6] + r[7]));
    }

    float dmin = __builtin_inff();
    int best = 0;
#pragma unroll 1
    for (int k = 0; k < K; k += 4) {
        const float* e0 = E + k * C;
        const float* e1 = e0 + C;
        const float* e2 = e0 + 2 * C;
        const float* e3 = e0 + 3 * C;
        float a0 = 0.0f, a1 = 0.0f, a2 = 0.0f, a3 = 0.0f;
#pragma unroll
        for (int c = 0; c < C; ++c) {
            float zc = z[c];
            a0 = __builtin_fmaf(zc, e0[c], a0);
            a1 = __builtin_fmaf(zc, e1[c], a1);
            a2 = __builtin_fmaf(zc, e2[c], a2);
            a3 = __builtin_fmaf(zc, e3[c], a3);
        }
        // fl(fl(zn+ek) - 2*a): 2*a is exact (power-of-two scale)
        float A0 = zn + ek[k];
        float A1 = zn + ek[k + 1];
        float A2 = zn + ek[k + 2];
        float A3 = zn + ek[k + 3];
        float d0 = A0 - 2.0f * a0;
        float d1 = A1 - 2.0f * a1;
        float d2 = A2 - 2.0f * a2;
        float d3 = A3 - 2.0f * a3;
        if (d0 < dmin) { dmin = d0; best = k; }
        if (d1 < dmin) { dmin = d1; best = k + 1; }
        if (d2 < dmin) { dmin = d2; best = k + 2; }
        if (d3 < dmin) { dmin = d3; best = k + 3; }
    }

    // epilogue: quantized output (straight-through double rounding), index,
    // loss partial. e-row gather vectorized as float4 (rows are 256B-aligned).
    const float4* eb4 = (const float4*)(E + best * C);
    float* o0 = out + b * (C * HW) + hw;
    float ls = 0.0f;
#pragma unroll
    for (int c4 = 0; c4 < 16; ++c4) {
        float4 e4 = eb4[c4];
        float e0 = e4.x, e1 = e4.y, e2 = e4.z, e3 = e4.w;
        int cb = c4 * 4;
        float d0 = e0 - z[cb + 0];
        float q0 = z[cb + 0] + d0;
        o0[(cb + 0) * HW] = q0;
        ls += d0 * d0;
        float d1 = e1 - z[cb + 1];
        float q1 = z[cb + 1] + d1;
        o0[(cb + 1) * HW] = q1;
        ls += d1 * d1;
        float d2 = e2 - z[cb + 2];
        float q2 = z[cb + 2] + d2;
        o0[(cb + 2) * HW] = q2;
        ls += d2 * d2;
        float d3 = e3 - z[cb + 3];
        float q3 = z[cb + 3] + d3;
        o0[(cb + 3) * HW] = q3;
        ls += d3 * d3;
    }
    out[OUT0 + n] = (float)best;  // indices region, as float

    // deterministic wave-64 butterfly reduce
#pragma unroll
    for (int off = 32; off > 0; off >>= 1) ls += __shfl_xor(ls, off, 64);
    int wid = n >> 6;
    if ((threadIdx.x & 63) == 0) partials[wid] = ls;
}

// ---------------------------------------------------------------------------
// Kernel 3: deterministic final loss reduction in fp64.
// loss = m + 0.25*m, m = mean(diff^2)  (both loss terms are numerically equal)
// ---------------------------------------------------------------------------
__global__ __launch_bounds__(256) void loss_kernel(const float* __restrict__ partials,
                                                   float* __restrict__ out) {
    __shared__ double sm[256];
    int t = threadIdx.x;
    double s = 0.0;
    for (int i = t; i < (N_TOTAL / 64); i += 256) s += (double)partials[i];
    sm[t] = s;
    __syncthreads();
    for (int o = 128; o > 0; o >>= 1) {
        if (t < o) sm[t] += sm[t + o];
        __syncthreads();
    }
    if (t == 0) {
        float m = (float)(sm[0] * (1.0 / 8388608.0));  // /2^23 exact scale
        float loss = m + 0.25f * m;
        out[OUT0 + N_TOTAL] = loss;
    }
}

extern "C" void kernel_launch(void* const* d_in, const int* in_sizes, int n_in,
                              void* d_out, int out_size, void* d_ws, size_t ws_size,
                              hipStream_t stream) {
    const float* Z = (const float*)d_in[0];   // [32,64,64,64] fp32
    const float* E = (const float*)d_in[1];   // [1024,64] fp32
    float* out = (float*)d_out;
    float* ek = (float*)d_ws;                 // 1024 floats
    float* partials = ek + K;                 // 2048 floats

    hipLaunchKernelGGL(ek_kernel, dim3(4), dim3(256), 0, stream, E, ek);
    hipLaunchKernelGGL(vq_kernel, dim3(N_TOTAL / 256), dim3(256), 0, stream,
                       Z, E, ek, out, partials);
    hipLaunchKernelGGL(loss_kernel, dim3(1), dim3(256), 0, stream, partials, out);
}

// Round 3
// 347.945 us; speedup vs baseline: 1.7883x; 1.3635x over previous
//
#include <hip/hip_runtime.h>

#define C 64
#define K 1024
#define HW 4096
#define N_TOTAL 131072   // 32*64*64
#define OUT0 8388608     // 32*64*64*64 (z_q_out elements)

// d_ws float layout
#define WS_EK        0
#define WS_PARTIALS  1024
#define WS_PD        3072                 // 2*N_TOTAL floats
#define WS_PI        (3072 + 2*N_TOTAL)  // 2*N_TOTAL ints
#define WS_NEED_FLOATS (3072 + 4*N_TOTAL)

// ---------------------------------------------------------------------------
// Kernel 1: ||e_k||^2, numpy pairwise 8-accumulator order, no contraction.
// ---------------------------------------------------------------------------
__global__ __launch_bounds__(256) void ek_kernel(const float* __restrict__ E,
                                                 float* __restrict__ ek) {
#pragma clang fp contract(off)
    int k = blockIdx.x * 256 + threadIdx.x;
    if (k >= K) return;
    const float* e = E + k * C;
    float r[8];
#pragma unroll
    for (int j = 0; j < 8; ++j) { float v = e[j]; r[j] = v * v; }
#pragma unroll
    for (int i = 8; i < C; i += 8) {
#pragma unroll
        for (int j = 0; j < 8; ++j) { float v = e[i + j]; r[j] += v * v; }
    }
    ek[k] = ((r[0] + r[1]) + (r[2] + r[3])) + ((r[4] + r[5]) + (r[6] + r[7]));
}

// ---------------------------------------------------------------------------
// Shared device helpers: z load + zn (numerics FROZEN, absmax 0.0 in R1/R2)
// ---------------------------------------------------------------------------
__device__ __forceinline__ void load_z_and_zn(const float* __restrict__ zp,
                                              float* z, float& zn) {
#pragma clang fp contract(off)
#pragma unroll
    for (int c = 0; c < C; ++c) z[c] = zp[c * HW];
    float r[8];
#pragma unroll
    for (int j = 0; j < 8; ++j) r[j] = z[j] * z[j];
#pragma unroll
    for (int i = 8; i < C; i += 8) {
#pragma unroll
        for (int j = 0; j < 8; ++j) r[j] += z[i + j] * z[i + j];
    }
    zn = ((r[0] + r[1]) + (r[2] + r[3])) + ((r[4] + r[5]) + (r[6] + r[7]));
    // PIN z into VGPRs: opaque to the compiler -> cannot re-load from global
    // inside the K-loop (R1/R2 allocated only 48 VGPRs and re-streamed z).
#pragma unroll
    for (int c = 0; c < C; ++c) asm volatile("" : "+v"(z[c]));
}

// ---------------------------------------------------------------------------
// Kernel 2a: split-K argmin. Split s scans codes [s*512, s*512+512) with the
// frozen strict-< ascending scan; writes (dmin, best) per (n, s).
// blk layout: s = blk&1 so the two splits of the same n-range are adjacent
// (same XCD L2 for the shared z rows).
// ---------------------------------------------------------------------------
__global__ __launch_bounds__(256, 4) void vq_argmin(const float* __restrict__ Z,
                                                    const float* __restrict__ E,
                                                    const float* __restrict__ ek,
                                                    float* __restrict__ pd,
                                                    int* __restrict__ pi) {
#pragma clang fp contract(off)
    int s = blockIdx.x & 1;
    int n = (blockIdx.x >> 1) * 256 + threadIdx.x;
    int b = n >> 12;
    int hw = n & 4095;

    float z[C], zn;
    load_z_and_zn(Z + b * (C * HW) + hw, z, zn);

    const int k0 = s * (K / 2);
    float dmin = __builtin_inff();
    int best = k0;
#pragma unroll 1
    for (int k = k0; k < k0 + K / 2; k += 4) {
        const float* e0 = E + k * C;
        float a0 = 0.0f, a1 = 0.0f, a2 = 0.0f, a3 = 0.0f;
#pragma unroll
        for (int c = 0; c < C; ++c) {
            float zc = z[c];
            a0 = __builtin_fmaf(zc, e0[c], a0);
            a1 = __builtin_fmaf(zc, e0[C + c], a1);
            a2 = __builtin_fmaf(zc, e0[2 * C + c], a2);
            a3 = __builtin_fmaf(zc, e0[3 * C + c], a3);
        }
        float A0 = zn + ek[k];
        float A1 = zn + ek[k + 1];
        float A2 = zn + ek[k + 2];
        float A3 = zn + ek[k + 3];
        float d0 = A0 - 2.0f * a0;   // 2a exact -> rounding identical to ref
        float d1 = A1 - 2.0f * a1;
        float d2 = A2 - 2.0f * a2;
        float d3 = A3 - 2.0f * a3;
        if (d0 < dmin) { dmin = d0; best = k; }
        if (d1 < dmin) { dmin = d1; best = k + 1; }
        if (d2 < dmin) { dmin = d2; best = k + 2; }
        if (d3 < dmin) { dmin = d3; best = k + 3; }
    }
    pd[s * N_TOTAL + n] = dmin;
    pi[s * N_TOTAL + n] = best;
}

// ---------------------------------------------------------------------------
// Kernel 2b: combine splits (tie -> split 0 == lower index, matching numpy's
// ascending strict-< scan) + epilogue identical to R2 (absmax 0.0).
// ---------------------------------------------------------------------------
__global__ __launch_bounds__(256) void vq_epilogue(const float* __restrict__ Z,
                                                   const float* __restrict__ E,
                                                   const float* __restrict__ pd,
                                                   const int* __restrict__ pi,
                                                   float* __restrict__ out,
                                                   float* __restrict__ partials) {
#pragma clang fp contract(off)
    int n = blockIdx.x * 256 + threadIdx.x;
    int b = n >> 12;
    int hw = n & 4095;

    float d0 = pd[n], d1 = pd[N_TOTAL + n];
    int best = (d1 < d0) ? pi[N_TOTAL + n] : pi[n];

    const float* zp = Z + b * (C * HW) + hw;
    const float4* eb4 = (const float4*)(E + best * C);
    float* o0 = out + b * (C * HW) + hw;
    float ls = 0.0f;
#pragma unroll
    for (int c4 = 0; c4 < 16; ++c4) {
        float4 e4 = eb4[c4];
        int cb = c4 * 4;
        float z0 = zp[(cb + 0) * HW], z1 = zp[(cb + 1) * HW];
        float z2 = zp[(cb + 2) * HW], z3 = zp[(cb + 3) * HW];
        float f0 = e4.x - z0; o0[(cb + 0) * HW] = z0 + f0; ls += f0 * f0;
        float f1 = e4.y - z1; o0[(cb + 1) * HW] = z1 + f1; ls += f1 * f1;
        float f2 = e4.z - z2; o0[(cb + 2) * HW] = z2 + f2; ls += f2 * f2;
        float f3 = e4.w - z3; o0[(cb + 3) * HW] = z3 + f3; ls += f3 * f3;
    }
    out[OUT0 + n] = (float)best;

#pragma unroll
    for (int off = 32; off > 0; off >>= 1) ls += __shfl_xor(ls, off, 64);
    if ((threadIdx.x & 63) == 0) partials[n >> 6] = ls;
}

// ---------------------------------------------------------------------------
// Fallback combined kernel (small ws): R2 structure + z pinning.
// ---------------------------------------------------------------------------
__global__ __launch_bounds__(256, 4) void vq_combined(const float* __restrict__ Z,
                                                      const float* __restrict__ E,
                                                      const float* __restrict__ ek,
                                                      float* __restrict__ out,
                                                      float* __restrict__ partials) {
#pragma clang fp contract(off)
    int n = blockIdx.x * 256 + threadIdx.x;
    int b = n >> 12;
    int hw = n & 4095;

    float z[C], zn;
    load_z_and_zn(Z + b * (C * HW) + hw, z, zn);

    float dmin = __builtin_inff();
    int best = 0;
#pragma unroll 1
    for (int k = 0; k < K; k += 4) {
        const float* e0 = E + k * C;
        float a0 = 0.0f, a1 = 0.0f, a2 = 0.0f, a3 = 0.0f;
#pragma unroll
        for (int c = 0; c < C; ++c) {
            float zc = z[c];
            a0 = __builtin_fmaf(zc, e0[c], a0);
            a1 = __builtin_fmaf(zc, e0[C + c], a1);
            a2 = __builtin_fmaf(zc, e0[2 * C + c], a2);
            a3 = __builtin_fmaf(zc, e0[3 * C + c], a3);
        }
        float A0 = zn + ek[k];
        float A1 = zn + ek[k + 1];
        float A2 = zn + ek[k + 2];
        float A3 = zn + ek[k + 3];
        float d0 = A0 - 2.0f * a0;
        float d1 = A1 - 2.0f * a1;
        float d2 = A2 - 2.0f * a2;
        float d3 = A3 - 2.0f * a3;
        if (d0 < dmin) { dmin = d0; best = k; }
        if (d1 < dmin) { dmin = d1; best = k + 1; }
        if (d2 < dmin) { dmin = d2; best = k + 2; }
        if (d3 < dmin) { dmin = d3; best = k + 3; }
    }

    const float4* eb4 = (const float4*)(E + best * C);
    float* o0 = out + b * (C * HW) + hw;
    float ls = 0.0f;
#pragma unroll
    for (int c4 = 0; c4 < 16; ++c4) {
        float4 e4 = eb4[c4];
        int cb = c4 * 4;
        float f0 = e4.x - z[cb + 0]; o0[(cb + 0) * HW] = z[cb + 0] + f0; ls += f0 * f0;
        float f1 = e4.y - z[cb + 1]; o0[(cb + 1) * HW] = z[cb + 1] + f1; ls += f1 * f1;
        float f2 = e4.z - z[cb + 2]; o0[(cb + 2) * HW] = z[cb + 2] + f2; ls += f2 * f2;
        float f3 = e4.w - z[cb + 3]; o0[(cb + 3) * HW] = z[cb + 3] + f3; ls += f3 * f3;
    }
    out[OUT0 + n] = (float)best;

#pragma unroll
    for (int off = 32; off > 0; off >>= 1) ls += __shfl_xor(ls, off, 64);
    if ((threadIdx.x & 63) == 0) partials[n >> 6] = ls;
}

// ---------------------------------------------------------------------------
// Kernel 3: deterministic final loss reduction in fp64 (frozen).
// ---------------------------------------------------------------------------
__global__ __launch_bounds__(256) void loss_kernel(const float* __restrict__ partials,
                                                   float* __restrict__ out) {
    __shared__ double sm[256];
    int t = threadIdx.x;
    double s = 0.0;
    for (int i = t; i < (N_TOTAL / 64); i += 256) s += (double)partials[i];
    sm[t] = s;
    __syncthreads();
    for (int o = 128; o > 0; o >>= 1) {
        if (t < o) sm[t] += sm[t + o];
        __syncthreads();
    }
    if (t == 0) {
        float m = (float)(sm[0] * (1.0 / 8388608.0));
        float loss = m + 0.25f * m;
        out[OUT0 + N_TOTAL] = loss;
    }
}

extern "C" void kernel_launch(void* const* d_in, const int* in_sizes, int n_in,
                              void* d_out, int out_size, void* d_ws, size_t ws_size,
                              hipStream_t stream) {
    const float* Z = (const float*)d_in[0];
    const float* E = (const float*)d_in[1];
    float* out = (float*)d_out;
    float* ws = (float*)d_ws;
    float* ek = ws + WS_EK;
    float* partials = ws + WS_PARTIALS;

    hipLaunchKernelGGL(ek_kernel, dim3(4), dim3(256), 0, stream, E, ek);

    if (ws_size >= (size_t)WS_NEED_FLOATS * sizeof(float)) {
        float* pd = ws + WS_PD;
        int* pi = (int*)(ws + WS_PI);
        hipLaunchKernelGGL(vq_argmin, dim3(N_TOTAL / 256 * 2), dim3(256), 0, stream,
                           Z, E, ek, pd, pi);
        hipLaunchKernelGGL(vq_epilogue, dim3(N_TOTAL / 256), dim3(256), 0, stream,
                           Z, E, pd, pi, out, partials);
    } else {
        hipLaunchKernelGGL(vq_combined, dim3(N_TOTAL / 256), dim3(256), 0, stream,
                           Z, E, ek, out, partials);
    }
    hipLaunchKernelGGL(loss_kernel, dim3(1), dim3(256), 0, stream, partials, out);
}

// Round 4
// 249.178 us; speedup vs baseline: 2.4971x; 1.3964x over previous
//
#include <hip/hip_runtime.h>

#define C 64
#define K 1024
#define HW 4096
#define N_TOTAL 131072   // 32*64*64
#define OUT0 8388608     // 32*64*64*64 (z_q_out elements)
#define MT 128           // n-rows per block
#define KT 128           // codes per K-tile
#define NTILES (K / KT)

// d_ws float layout
#define WS_EK        0
#define WS_PARTIALS  1024
#define WS_BEST      3072                 // N_TOTAL ints
#define WS_NEED_FLOATS (3072 + N_TOTAL)

typedef unsigned int u32;
typedef unsigned long long u64;

// monotone float map + index pack: lexicographic min == (min d, then min k)
__device__ __forceinline__ u64 packdk(float d, int k) {
    u32 b = __float_as_uint(d);
    u32 m = b ^ ((u32)((int)b >> 31) | 0x80000000u);
    return ((u64)m << 32) | (u32)k;
}

// ---------------------------------------------------------------------------
// Kernel 1: ||e_k||^2, numpy pairwise 8-accumulator order, no contraction.
// (FROZEN: absmax 0.0 in R1-R3)
// ---------------------------------------------------------------------------
__global__ __launch_bounds__(256) void ek_kernel(const float* __restrict__ E,
                                                 float* __restrict__ ek) {
#pragma clang fp contract(off)
    int k = blockIdx.x * 256 + threadIdx.x;
    if (k >= K) return;
    const float* e = E + k * C;
    float r[8];
#pragma unroll
    for (int j = 0; j < 8; ++j) { float v = e[j]; r[j] = v * v; }
#pragma unroll
    for (int i = 8; i < C; i += 8) {
#pragma unroll
        for (int j = 0; j < 8; ++j) { float v = e[i + j]; r[j] += v * v; }
    }
    ek[k] = ((r[0] + r[1]) + (r[2] + r[3])) + ((r[4] + r[5]) + (r[6] + r[7]));
}

// ---------------------------------------------------------------------------
// Kernel 2: register-blocked VALU GEMM argmin.
// Block: 128 n-rows x 1024 codes (8 K-tiles of 128). 256 threads, each owns
// an 8n x 8q accumulator tile -> 64 fma per c-step vs 4 ds_read_b128.
// Lane map: i = lane&7 (n-group), j = lane>>3 (k-group); both LDS read
// patterns are 8-distinct-address / 2-way-bank = conflict-free (m136).
// Numerics FROZEN: per-(n,k) dot = sequential fma over c=0..63 (identical to
// R3); d = fl(fl(zn+ek) - 2a); argmin = lexicographic min of (mono(d), k).
// ---------------------------------------------------------------------------
__global__ __launch_bounds__(256, 2) void vq_gemm(const float* __restrict__ Z,
                                                  const float* __restrict__ E,
                                                  const float* __restrict__ ek,
                                                  int* __restrict__ bestArr) {
#pragma clang fp contract(off)
    __shared__ float Zt[C * MT];     // [c][n_local]  32 KB
    __shared__ float Et[C * KT];     // [c][k_local]  32 KB
    __shared__ float znbuf[MT];
    __shared__ u64 red[4][8][8];     // [wave][i_l][m]

    const int t = threadIdx.x;
    const int n0 = blockIdx.x * MT;
    const int b = n0 >> 12;
    const int hw0 = n0 & 4095;
    const float* zbase = Z + b * (C * HW) + hw0;

    // ---- stage Zt (global layout already [c][n]-contiguous: coalesced) ----
#pragma unroll
    for (int r = 0; r < 8; ++r) {
        int idx4 = r * 256 + t;
        int c = idx4 >> 5, n4 = idx4 & 31;
        float4 v = *(const float4*)(zbase + c * HW + n4 * 4);
        *(float4*)(&Zt[c * MT + n4 * 4]) = v;
    }
    __syncthreads();

    // ---- zn per row (numpy pairwise-8 order; contract OFF in scope) ----
    if (t < MT) {
        float r8[8];
#pragma unroll
        for (int j = 0; j < 8; ++j) { float v = Zt[j * MT + t]; r8[j] = v * v; }
#pragma unroll
        for (int i = 1; i < 8; ++i)
#pragma unroll
            for (int j = 0; j < 8; ++j) { float v = Zt[(i * 8 + j) * MT + t]; r8[j] += v * v; }
        znbuf[t] = ((r8[0] + r8[1]) + (r8[2] + r8[3])) + ((r8[4] + r8[5]) + (r8[6] + r8[7]));
    }
    __syncthreads();

    const int wave = t >> 6, lane = t & 63;
    const int i_l = lane & 7, j_l = lane >> 3;
    const int ig = ((wave & 1) << 3) | i_l;    // n-group 0..15
    const int jg = ((wave >> 1) << 3) | j_l;   // k-group 0..15

    float znm[8];
#pragma unroll
    for (int m = 0; m < 8; ++m) znm[m] = znbuf[ig * 8 + m];

    u64 bestp[8];
#pragma unroll
    for (int m = 0; m < 8; ++m) bestp[m] = ~0ull;

    for (int tile = 0; tile < NTILES; ++tile) {
        __syncthreads();   // previous tile's Et fully consumed
        // stage Et transposed [c][k]; ds_writes are lane-consecutive (t*4B)
        // -> conflict-free; global reads stride-256B but E is L2-hot (256KB).
        {
            int k_l = t & 127;
            int ch = t >> 7;
            const float* es = E + (tile * KT + k_l) * C + ch * 32;
#pragma unroll
            for (int r = 0; r < 8; ++r) {
                float4 v = *(const float4*)(es + r * 4);
                int c0 = ch * 32 + r * 4;
                Et[(c0 + 0) * KT + k_l] = v.x;
                Et[(c0 + 1) * KT + k_l] = v.y;
                Et[(c0 + 2) * KT + k_l] = v.z;
                Et[(c0 + 3) * KT + k_l] = v.w;
            }
        }
        __syncthreads();

        float ekq[8];
        {
            const float* ep = ek + tile * KT + jg * 8;
            float4 a = *(const float4*)ep;
            float4 bq = *(const float4*)(ep + 4);
            ekq[0] = a.x;  ekq[1] = a.y;  ekq[2] = a.z;  ekq[3] = a.w;
            ekq[4] = bq.x; ekq[5] = bq.y; ekq[6] = bq.z; ekq[7] = bq.w;
        }

        float acc[8][8];
#pragma unroll
        for (int m = 0; m < 8; ++m)
#pragma unroll
            for (int q = 0; q < 8; ++q) acc[m][q] = 0.0f;

#pragma unroll 8
        for (int c = 0; c < C; ++c) {
            float4 za = *(const float4*)(&Zt[c * MT + ig * 8]);
            float4 zb = *(const float4*)(&Zt[c * MT + ig * 8 + 4]);
            float4 ea = *(const float4*)(&Et[c * KT + jg * 8]);
            float4 eb = *(const float4*)(&Et[c * KT + jg * 8 + 4]);
            float zm[8] = {za.x, za.y, za.z, za.w, zb.x, zb.y, zb.z, zb.w};
            float eq[8] = {ea.x, ea.y, ea.z, ea.w, eb.x, eb.y, eb.z, eb.w};
#pragma unroll
            for (int m = 0; m < 8; ++m)
#pragma unroll
                for (int q = 0; q < 8; ++q)
                    acc[m][q] = __builtin_fmaf(zm[m], eq[q], acc[m][q]);
        }

#pragma unroll
        for (int m = 0; m < 8; ++m)
#pragma unroll
            for (int q = 0; q < 8; ++q) {
                float A = znm[m] + ekq[q];       // fl(zn+ek)
                float d = A - 2.0f * acc[m][q];  // 2a exact -> fl(A-2a)
                u64 p = packdk(d, tile * KT + jg * 8 + q);
                if (p < bestp[m]) bestp[m] = p;
            }
    }

    // reduce over j: lane bits 3,4,5 (in-wave butterfly), then cross-wave LDS
#pragma unroll
    for (int m = 0; m < 8; ++m) {
        u64 v = bestp[m];
#pragma unroll
        for (int mask = 8; mask <= 32; mask <<= 1) {
            u64 o = __shfl_xor(v, mask, 64);
            v = o < v ? o : v;
        }
        bestp[m] = v;
    }
    if (j_l == 0) {
#pragma unroll
        for (int m = 0; m < 8; ++m) red[wave][i_l][m] = bestp[m];
    }
    __syncthreads();
    if (t < MT) {
        int igg = t >> 3, m = t & 7;
        int ihalf = igg >> 3, iw = igg & 7;  // wave&1 == ihalf holds these i
        u64 a = red[ihalf][iw][m];
        u64 b2 = red[ihalf + 2][iw][m];
        u64 v = b2 < a ? b2 : a;
        bestArr[n0 + t] = (int)(v & 0xFFFFFFFFu);
    }
}

// ---------------------------------------------------------------------------
// Kernel 3: epilogue (FROZEN body from R2/R3, absmax 0.0): z_q straight-
// through double rounding, indices, loss partials.
// ---------------------------------------------------------------------------
__global__ __launch_bounds__(256) void vq_epilogue(const float* __restrict__ Z,
                                                   const float* __restrict__ E,
                                                   const int* __restrict__ bestArr,
                                                   float* __restrict__ out,
                                                   float* __restrict__ partials) {
#pragma clang fp contract(off)
    int n = blockIdx.x * 256 + threadIdx.x;
    int b = n >> 12;
    int hw = n & 4095;
    int best = bestArr[n];

    const float* zp = Z + b * (C * HW) + hw;
    const float4* eb4 = (const float4*)(E + best * C);
    float* o0 = out + b * (C * HW) + hw;
    float ls = 0.0f;
#pragma unroll
    for (int c4 = 0; c4 < 16; ++c4) {
        float4 e4 = eb4[c4];
        int cb = c4 * 4;
        float z0 = zp[(cb + 0) * HW], z1 = zp[(cb + 1) * HW];
        float z2 = zp[(cb + 2) * HW], z3 = zp[(cb + 3) * HW];
        float f0 = e4.x - z0; o0[(cb + 0) * HW] = z0 + f0; ls += f0 * f0;
        float f1 = e4.y - z1; o0[(cb + 1) * HW] = z1 + f1; ls += f1 * f1;
        float f2 = e4.z - z2; o0[(cb + 2) * HW] = z2 + f2; ls += f2 * f2;
        float f3 = e4.w - z3; o0[(cb + 3) * HW] = z3 + f3; ls += f3 * f3;
    }
    out[OUT0 + n] = (float)best;

#pragma unroll
    for (int off = 32; off > 0; off >>= 1) ls += __shfl_xor(ls, off, 64);
    if ((threadIdx.x & 63) == 0) partials[n >> 6] = ls;
}

// ---------------------------------------------------------------------------
// Fallback combined kernel (tiny ws): R2 structure.
// ---------------------------------------------------------------------------
__global__ __launch_bounds__(256, 4) void vq_combined(const float* __restrict__ Z,
                                                      const float* __restrict__ E,
                                                      const float* __restrict__ ek,
                                                      float* __restrict__ out,
                                                      float* __restrict__ partials) {
#pragma clang fp contract(off)
    int n = blockIdx.x * 256 + threadIdx.x;
    int b = n >> 12;
    int hw = n & 4095;
    const float* zp = Z + b * (C * HW) + hw;

    float z[C];
#pragma unroll
    for (int c = 0; c < C; ++c) z[c] = zp[c * HW];
    float zn;
    {
        float r[8];
#pragma unroll
        for (int j = 0; j < 8; ++j) r[j] = z[j] * z[j];
#pragma unroll
        for (int i = 8; i < C; i += 8) {
#pragma unroll
            for (int j = 0; j < 8; ++j) r[j] += z[i + j] * z[i + j];
        }
        zn = ((r[0] + r[1]) + (r[2] + r[3])) + ((r[4] + r[5]) + (r[6] + r[7]));
    }

    float dmin = __builtin_inff();
    int best = 0;
#pragma unroll 1
    for (int k = 0; k < K; k += 4) {
        const float* e0 = E + k * C;
        float a0 = 0.0f, a1 = 0.0f, a2 = 0.0f, a3 = 0.0f;
#pragma unroll
        for (int c = 0; c < C; ++c) {
            float zc = z[c];
            a0 = __builtin_fmaf(zc, e0[c], a0);
            a1 = __builtin_fmaf(zc, e0[C + c], a1);
            a2 = __builtin_fmaf(zc, e0[2 * C + c], a2);
            a3 = __builtin_fmaf(zc, e0[3 * C + c], a3);
        }
        float A0 = zn + ek[k],     A1 = zn + ek[k + 1];
        float A2 = zn + ek[k + 2], A3 = zn + ek[k + 3];
        float d0 = A0 - 2.0f * a0, d1 = A1 - 2.0f * a1;
        float d2 = A2 - 2.0f * a2, d3 = A3 - 2.0f * a3;
        if (d0 < dmin) { dmin = d0; best = k; }
        if (d1 < dmin) { dmin = d1; best = k + 1; }
        if (d2 < dmin) { dmin = d2; best = k + 2; }
        if (d3 < dmin) { dmin = d3; best = k + 3; }
    }

    const float4* eb4 = (const float4*)(E + best * C);
    float* o0 = out + b * (C * HW) + hw;
    float ls = 0.0f;
#pragma unroll
    for (int c4 = 0; c4 < 16; ++c4) {
        float4 e4 = eb4[c4];
        int cb = c4 * 4;
        float f0 = e4.x - z[cb + 0]; o0[(cb + 0) * HW] = z[cb + 0] + f0; ls += f0 * f0;
        float f1 = e4.y - z[cb + 1]; o0[(cb + 1) * HW] = z[cb + 1] + f1; ls += f1 * f1;
        float f2 = e4.z - z[cb + 2]; o0[(cb + 2) * HW] = z[cb + 2] + f2; ls += f2 * f2;
        float f3 = e4.w - z[cb + 3]; o0[(cb + 3) * HW] = z[cb + 3] + f3; ls += f3 * f3;
    }
    out[OUT0 + n] = (float)best;
#pragma unroll
    for (int off = 32; off > 0; off >>= 1) ls += __shfl_xor(ls, off, 64);
    if ((threadIdx.x & 63) == 0) partials[n >> 6] = ls;
}

// ---------------------------------------------------------------------------
// Kernel 4: deterministic final loss reduction in fp64 (frozen).
// ---------------------------------------------------------------------------
__global__ __launch_bounds__(256) void loss_kernel(const float* __restrict__ partials,
                                                   float* __restrict__ out) {
    __shared__ double sm[256];
    int t = threadIdx.x;
    double s = 0.0;
    for (int i = t; i < (N_TOTAL / 64); i += 256) s += (double)partials[i];
    sm[t] = s;
    __syncthreads();
    for (int o = 128; o > 0; o >>= 1) {
        if (t < o) sm[t] += sm[t + o];
        __syncthreads();
    }
    if (t == 0) {
        float m = (float)(sm[0] * (1.0 / 8388608.0));
        float loss = m + 0.25f * m;
        out[OUT0 + N_TOTAL] = loss;
    }
}

extern "C" void kernel_launch(void* const* d_in, const int* in_sizes, int n_in,
                              void* d_out, int out_size, void* d_ws, size_t ws_size,
                              hipStream_t stream) {
    const float* Z = (const float*)d_in[0];
    const float* E = (const float*)d_in[1];
    float* out = (float*)d_out;
    float* ws = (float*)d_ws;
    float* ek = ws + WS_EK;
    float* partials = ws + WS_PARTIALS;

    hipLaunchKernelGGL(ek_kernel, dim3(4), dim3(256), 0, stream, E, ek);

    if (ws_size >= (size_t)WS_NEED_FLOATS * sizeof(float)) {
        int* bestArr = (int*)(ws + WS_BEST);
        hipLaunchKernelGGL(vq_gemm, dim3(N_TOTAL / MT), dim3(256), 0, stream,
                           Z, E, ek, bestArr);
        hipLaunchKernelGGL(vq_epilogue, dim3(N_TOTAL / 256), dim3(256), 0, stream,
                           Z, E, bestArr, out, partials);
    } else {
        hipLaunchKernelGGL(vq_combined, dim3(N_TOTAL / 256), dim3(256), 0, stream,
                           Z, E, ek, out, partials);
    }
    hipLaunchKernelGGL(loss_kernel, dim3(1), dim3(256), 0, stream, partials, out);
}